// Round 6
// baseline (208.041 us; speedup 1.0000x reference)
//
#include <hip/hip_runtime.h>

// VACF via banded-Gram MFMA, round 15.
// G[t] = sum_i X[i][:] . X[i+t][:]  (t=0..99), X = [T=10000, C=3000] fp32.
//
// R14 post-mortem: single-shot staging (72KB in flight/block) did NOT beat
// depth-1 prefetch -- convoy theory dead. Invariant across R12/R14: main
// stages 94.4MB in ~66-71us = 5.6 B/cyc/CU regardless of structure. That is
// a completion-window fingerprint: ~4 outstanding 1-KB global_load_lds fills
// per CU x ~700cyc L2-miss latency = 5.9 B/cyc/CU. m97's 28 TB/s gload_lds
// had an L2-HIT source; our Y (63.7MB >> 4MB L2/XCD) misses L2. Register
// loads have no such window (R9/R10: 2.2 TB/s despite 8-seg fan-out;
// 18 indep loads/lane x 8 waves/CU = ~144KB in flight/CU).
// R15 (ONE kernel changed for attribution; relayout bit-identical to R14):
//  - main staging: 18 per-lane float4 register loads (contiguous 1-KB
//    wave-instrs from chunk-major Y) then 18 conflict-free ds_write_b128,
//    fully unrolled, all loads issued before first store. Single-shot +
//    one barrier + compute loop unchanged.
// Predict: staging 1.4 -> ~5-6 TB/s, main 66 -> ~20-25us, bench 208 -> ~163.
// If total doesn't drop >=30us: DMA-window theory falsified -> R16 goes
// single-pass from X (ws read path itself suspect).

#define T_DIM 10000
#define C_DIM 3000
#define W 100

// relayout geometry
#define CHUNKS 96            // 32-col chunks (3000 -> 94 -> pad to 96)
#define RPAD 10368           // padded rows (max staged row 9984+384)
#define GRAN 64              // bytes per (chunk,row) granule = 32 bf16
#define PITCH 576            // relayout LDS tile pitch (bytes); 144w==16 mod 32
#define YOFF 4096            // Y offset in ws; partial[] at ws+0
#define WS_NEED (YOFF + (size_t)CHUNKS * RPAD * GRAN)

// main kernel geometry
#define MA 256               // A rows per block
#define NA 16                // A subblocks of 16
#define SROWS 384            // staged rows (A + band to subblock 23)
#define NBB 40               // 40*256 = 10240 >= 10000
#define KSPLIT 32            // k-slices of CPB chunks
#define CPB 3                // 32*3 = 96 chunks
#define CTILE (SROWS * GRAN) // 24576 B per chunk tile
#define NPART 8

// fallback (R10) geometry
#define FB_MA 112
#define FB_NA 7
#define FB_SROWS 224
#define FB_NBB 90
#define FB_KSPLIT 24
#define FB_CPB 4
#define FB_KB 32
#define FB_LPAD 34

typedef __attribute__((ext_vector_type(8))) short short8;    // 8 bf16
typedef __attribute__((ext_vector_type(4))) short short4v;   // 4 bf16
typedef __attribute__((ext_vector_type(4))) float float4v;
typedef __attribute__((ext_vector_type(4))) unsigned int uint4v;

__device__ __forceinline__ short f2bf(float f) {   // RNE fp32->bf16 (finite)
    unsigned u = __float_as_uint(f);
    u += 0x7fffu + ((u >> 16) & 1u);
    return (short)(u >> 16);
}

__device__ __forceinline__ float4v ntload4(const float* p) {
    return __builtin_nontemporal_load((const float4v*)p);
}

// ---------------------------------------------------------------------------
// Kernel 1: X fp32 row-major -> Y bf16 chunk-major with baked sigma swizzle.
// Granule (c, r) holds cols 32c + 8*(p ^ sigma(r)) .. +7 at slot position p,
// sigma(r) = (r>>1)&3. Zero outside [0,10000) x [0,3000).
// Block: 64 rows x 256 cols.  (bit-identical to R14)
// ---------------------------------------------------------------------------
__global__ __launch_bounds__(256)
void vacf_relayout(const float* __restrict__ X, char* __restrict__ Y) {
    __shared__ __align__(16) char tile[64 * PITCH];   // 36.9 KB
    const int tid = threadIdx.x;
    const int l   = tid & 63;
    const int w   = tid >> 6;
    const int bc  = blockIdx.x % 12;       // col-group (256 cols)
    const int br  = blockIdx.x / 12;       // row-group (64 rows)
    const int r0  = br * 64;
    const int c0  = bc * 256;

    // phase 1: coalesced read of X[64r x 256c], convert, swizzled LDS store.
    // wave w, iter k: row rl = k*4 + w, lane covers cols 4l..4l+3 (1KB/wave).
    const bool interior = (r0 + 64 <= T_DIM) && (c0 + 256 <= C_DIM);
    if (interior) {
        #pragma unroll
        for (int k = 0; k < 16; ++k) {
            const int rl  = k * 4 + w;
            const int col = l * 4;
            const float4v v = ntload4(X + (size_t)(r0 + rl) * C_DIM + c0 + col);
            short4v o;
            o[0] = f2bf(v[0]); o[1] = f2bf(v[1]); o[2] = f2bf(v[2]); o[3] = f2bf(v[3]);
            const int cc = col >> 5, p = (col >> 3) & 3, sub = col & 7;
            const int ps = p ^ ((rl >> 1) & 3);
            *(short4v*)&tile[rl * PITCH + cc * 64 + ps * 16 + sub * 2] = o;
        }
    } else {
        #pragma unroll
        for (int k = 0; k < 16; ++k) {
            const int rl  = k * 4 + w;
            const int col = l * 4;
            const int row = r0 + rl;
            float4v v = {0.f, 0.f, 0.f, 0.f};
            if (row < T_DIM && c0 + col + 4 <= C_DIM)   // 3000%4==0: no straddle
                v = *(const float4v*)(X + (size_t)row * C_DIM + c0 + col);
            short4v o;
            o[0] = f2bf(v[0]); o[1] = f2bf(v[1]); o[2] = f2bf(v[2]); o[3] = f2bf(v[3]);
            const int cc = col >> 5, p = (col >> 3) & 3, sub = col & 7;
            const int ps = p ^ ((rl >> 1) & 3);
            *(short4v*)&tile[rl * PITCH + cc * 64 + ps * 16 + sub * 2] = o;
        }
    }
    __syncthreads();

    // phase 2: wave w owns rows [16w, 16w+16); lane (rl = 16w + l>>2, q = l&3)
    // -> every wave-store is a fully contiguous 1KB span of Y.
    const int rl = 16 * w + (l >> 2);
    const int q  = l & 3;
    const char* s = &tile[rl * PITCH + q * 16];
    #pragma unroll
    for (int cc = 0; cc < 8; ++cc) {
        char* dst = Y + ((size_t)(bc * 8 + cc) * RPAD + r0 + rl) * GRAN + q * 16;
        *(uint4v*)dst = *(const uint4v*)(s + cc * 64);
    }
}

// ---------------------------------------------------------------------------
// Kernel 2: banded-Gram MFMA from chunk-major Y. Single-shot REGISTER
// staging: 18 contiguous 1-KB wave-loads -> 18 ds_write_b128, one barrier,
// then barrier-free compute. 2 blocks/CU co-resident.
// ---------------------------------------------------------------------------
__global__ __launch_bounds__(256, 2)
void vacf_main(const char* __restrict__ Y, float* __restrict__ partial) {
    const int tid  = threadIdx.x;
    const int lane = tid & 63;
    const int wv   = tid >> 6;
    const int xcd  = blockIdx.x & 7;
    const int j    = blockIdx.x >> 3;          // 0..159, consecutive on XCD
    const int ksix = xcd + 8 * (j / NBB);      // k-slice 0..31, XCD-constant/sweep
    const int bb   = j % NBB;                  // row-block, consecutive on XCD
    const int i0   = bb * MA;                  // mult of 256 -> sigma local

    __shared__ __align__(16) char lds[CPB * CTILE];   // 73.7 KB
    __shared__ float bins[W];
    if (tid < W) bins[tid] = 0.f;

    const int n    = lane & 15;
    const int quad = lane >> 4;
    const int d0   = 2 * wv;                   // wave's diagonal pair d0, d0+1
    // fragment base: row n, slot quad ^ sigma(n); row R=16s+n adds s*1024.
    const int fragoff = n * 64 + ((quad ^ ((n >> 1) & 3)) << 4);
    const int lr16 = lane * 16;

    // stage: wave wv owns rows [wv*96, wv*96+96) of each of the 3 chunks.
    // 18 independent 1-KB contiguous wave-loads (all in flight), then 18
    // conflict-free ds_write_b128 (lane-consecutive 16B).
    uint4v rg[CPB * 6];
    #pragma unroll
    for (int cc = 0; cc < CPB; ++cc) {
        const char* sb = Y + ((size_t)(ksix * CPB + cc) * RPAD + i0 + wv * 96) * GRAN + lr16;
        #pragma unroll
        for (int m = 0; m < 6; ++m)
            rg[cc * 6 + m] = *(const uint4v*)(sb + m * 1024);
    }
    #pragma unroll
    for (int cc = 0; cc < CPB; ++cc) {
        char* db = lds + cc * CTILE + wv * 96 * GRAN + lr16;
        #pragma unroll
        for (int m = 0; m < 6; ++m)
            *(uint4v*)(db + m * 1024) = rg[cc * 6 + m];
    }
    __syncthreads();                           // tile ready (and bins init)

    float4v acc0 = {0.f, 0.f, 0.f, 0.f};
    float4v acc1 = {0.f, 0.f, 0.f, 0.f};

    #pragma unroll
    for (int cc = 0; cc < CPB; ++cc) {
        const char* lb = lds + cc * CTILE + fragoff;
        short8 fbp = *(const short8*)(lb + d0 * 1024);       // B subblock d0
        #pragma unroll
        for (int a = 0; a < NA; ++a) {
            const short8 fav = *(const short8*)(lb + a * 1024);
            const short8 fbn = *(const short8*)(lb + (d0 + a + 1) * 1024);
            acc0 = __builtin_amdgcn_mfma_f32_16x16x32_bf16(fav, fbp, acc0, 0, 0, 0);
            acc1 = __builtin_amdgcn_mfma_f32_16x16x32_bf16(fav, fbn, acc1, 0, 0, 0);
            fbp = fbn;
        }
    }

    // epilogue: D[m][n] of diagonal d -> lag t = 16d + n - m  (m = quad*4 + p)
    #pragma unroll
    for (int p = 0; p < 4; ++p) {
        const int m  = quad * 4 + p;
        const int t0 = 16 * d0 + n - m;
        if (t0 >= 0 && t0 < W) atomicAdd(&bins[t0], acc0[p]);
        const int t1 = t0 + 16;
        if (t1 >= 0 && t1 < W) atomicAdd(&bins[t1], acc1[p]);
    }
    __syncthreads();
    if (tid < W) atomicAdd(&partial[xcd * W + tid], bins[tid]);
}

// ---------------------------------------------------------------------------
// Fallback (ws too small): R10 register-staging kernel, proven correct.
// ---------------------------------------------------------------------------
__global__ __launch_bounds__(256, 2)
void vacf_fb(const float* __restrict__ X, float* __restrict__ partial) {
    const int tid  = threadIdx.x;
    const int lane = tid & 63;
    const int wv   = tid >> 6;
    const int xcd  = blockIdx.x & 7;
    const int j    = blockIdx.x >> 3;
    const int ksix = xcd + 8 * (j / FB_NBB);
    const int bb   = j % FB_NBB;
    const int i0   = bb * FB_MA;
    const int ks   = ksix * (FB_CPB * FB_KB);
    const int ke   = (ks + FB_CPB * FB_KB < C_DIM) ? (ks + FB_CPB * FB_KB) : C_DIM;
    const int nit  = (ke - ks + FB_KB - 1) / FB_KB;

    __shared__ short buf[FB_SROWS * FB_LPAD];
    __shared__ float bins[W];
    if (tid < W) bins[tid] = 0.f;

    const int cp = tid & 7;
    const int r0 = tid >> 3;
    const int n    = lane & 15;
    const int quad = lane >> 4;
    const int d0   = 2 * wv;
    const short* fragbase = &buf[n * FB_LPAD + quad * 8];

    float4v acc0 = {0.f, 0.f, 0.f, 0.f};
    float4v acc1 = {0.f, 0.f, 0.f, 0.f};
    float4v pf[FB_NA];

    {
        #pragma unroll
        for (int s = 0; s < FB_NA; ++s) {
            const int row = i0 + r0 + 32 * s;
            const int col = ks + 4 * cp;
            pf[s] = (row < T_DIM) ? *(const float4v*)(X + (size_t)row * C_DIM + col)
                                  : (float4v){0.f, 0.f, 0.f, 0.f};
        }
    }

    #pragma unroll 1
    for (int it = 0; it < nit; ++it) {
        __syncthreads();
        #pragma unroll
        for (int s = 0; s < FB_NA; ++s) {
            short4v o;
            o[0] = f2bf(pf[s][0]); o[1] = f2bf(pf[s][1]);
            o[2] = f2bf(pf[s][2]); o[3] = f2bf(pf[s][3]);
            *(short4v*)&buf[(r0 + 32 * s) * FB_LPAD + 4 * cp] = o;
        }
        __syncthreads();

        if (it + 1 < nit) {
            const int k0 = ks + (it + 1) * FB_KB;
            const bool kfull = (k0 + FB_KB <= ke);
            #pragma unroll
            for (int s = 0; s < FB_NA; ++s) {
                const int row = i0 + r0 + 32 * s;
                const int col = k0 + 4 * cp;
                if ((row < T_DIM) & kfull) {
                    pf[s] = *(const float4v*)(X + (size_t)row * C_DIM + col);
                } else {
                    #pragma unroll
                    for (int e = 0; e < 4; ++e)
                        pf[s][e] = (row < T_DIM && col + e < ke)
                                     ? X[(size_t)row * C_DIM + col + e] : 0.f;
                }
            }
        }

        short8 fa[FB_NA], fb[8];
        #pragma unroll
        for (int a = 0; a < FB_NA; ++a)
            fa[a] = *(const short8*)(fragbase + 16 * a * FB_LPAD);
        #pragma unroll
        for (int u = 0; u < 8; ++u)
            fb[u] = *(const short8*)(fragbase + 16 * (d0 + u) * FB_LPAD);

        #pragma unroll
        for (int a = 0; a < FB_NA; ++a) {
            acc0 = __builtin_amdgcn_mfma_f32_16x16x32_bf16(fa[a], fb[a],     acc0, 0, 0, 0);
            acc1 = __builtin_amdgcn_mfma_f32_16x16x32_bf16(fa[a], fb[a + 1], acc1, 0, 0, 0);
        }
    }

    #pragma unroll
    for (int p = 0; p < 4; ++p) {
        const int m  = quad * 4 + p;
        const int t0 = 16 * d0 + n - m;
        if (t0 >= 0 && t0 < W) atomicAdd(&bins[t0], acc0[p]);
        const int t1 = t0 + 16;
        if (t1 >= 0 && t1 < W) atomicAdd(&bins[t1], acc1[p]);
    }
    __syncthreads();
    if (tid < W) atomicAdd(&partial[xcd * W + tid], bins[tid]);
}

__global__ void vacf_scale(const float* __restrict__ partial, float* __restrict__ out) {
    int t = threadIdx.x;
    if (t < W) {
        float s = 0.f;
        #pragma unroll
        for (int b = 0; b < NPART; ++b) s += partial[b * W + t];
        out[t] = s / ((float)(T_DIM - t) * (float)C_DIM);
    }
}

extern "C" void kernel_launch(void* const* d_in, const int* in_sizes, int n_in,
                              void* d_out, int out_size, void* d_ws, size_t ws_size,
                              hipStream_t stream) {
    const float* X = (const float*)d_in[0];
    float* out = (float*)d_out;
    float* ws  = (float*)d_ws;

    hipMemsetAsync(ws, 0, NPART * W * sizeof(float), stream);
    if (ws_size >= WS_NEED) {
        char* Y = (char*)d_ws + YOFF;
        vacf_relayout<<<(RPAD / 64) * 12, 256, 0, stream>>>(X, Y);
        vacf_main<<<NBB * KSPLIT, 256, 0, stream>>>(Y, ws);
    } else {
        vacf_fb<<<FB_NBB * FB_KSPLIT, 256, 0, stream>>>(X, ws);
    }
    vacf_scale<<<1, 128, 0, stream>>>(ws, out);
}

// Round 7
// 186.679 us; speedup vs baseline: 1.1144x; 1.1144x over previous
//
#include <hip/hip_runtime.h>

// VACF via banded-Gram MFMA, round 16: SINGLE-PASS.
// G[t] = sum_i X[i][:] . X[i+t][:]  (t=0..99), X = [T=10000, C=3000] fp32.
//
// R15 post-mortem: register staging (18 concurrent 1-KB wave-loads) ==
// gload_lds single-shot == gload_lds depth-1, to the microsecond. The
// DMA-window theory is dead. Cross-round invariant: every kernel variant
// runs its memory phase at 1.4-3 TB/s while harness fills hit 6.9 TB/s in
// the same window; no latency/BW arithmetic produces main's ~70us. Also:
// both kernels are below the top-5 cutoff -> no per-kernel attribution.
// R16: structural simplification that wins under every surviving theory --
// delete relayout+Y (two-pass moved 184+94 MB for ~132us). Single pass
// stages 185 MB fp32 straight from X:
//  - 64-col k-slices: wave-load = 4 x 256-B segments (2x fewer segs/instr
//    than R9's proven 2.2 TB/s pattern) at amp 1.54x (vs R9's 3x).
//  - LDS 384x64 bf16 = 48 KB, 3 blocks/CU, one barrier total.
//  - XOR swizzle (16-B slot ^= row&7 within 128-B rows): ds_write_b64 and
//    ds_read_b128 both conflict-free at quarter-wave granularity.
//  - staging: 3 batches of 8 independent float4 loads/lane (96 KB in
//    flight per CU at 12 waves/CU).
// Predict: fused 45-85us (re-enters top-5 if >=69 -> attribution back),
// FETCH 120-190 MB, total 208 -> 125-165. Falsifier: total unchanged =>
// systemic wall (clocks/power), not access pattern.

#define T_DIM 10000
#define C_DIM 3000
#define W 100
#define MA 256               // A rows per block
#define NA 16                // A subblocks of 16
#define SROWS 384            // staged rows (A + 128-row band)
#define NBB 40               // 40*256 = 10240 >= 10000
#define KS 47                // col-slices of KW (47*64 = 3008 >= 3000)
#define KW 64                // cols per slice (2 MFMA K-chunks)
#define NPART 8              // partial buckets (atomic spread)

typedef __attribute__((ext_vector_type(8))) short short8;    // 8 bf16
typedef __attribute__((ext_vector_type(4))) short short4v;   // 4 bf16
typedef __attribute__((ext_vector_type(4))) float float4v;

__device__ __forceinline__ short f2bf(float f) {   // RNE fp32->bf16 (finite)
    unsigned u = __float_as_uint(f);
    u += 0x7fffu + ((u >> 16) & 1u);
    return (short)(u >> 16);
}

// ---------------------------------------------------------------------------
// Single-pass kernel: stage X[i0..i0+384) x [c0..c0+64) fp32->bf16 into
// swizzled LDS, one barrier, banded-Gram MFMA, bin epilogue.
// LDS row = 64 bf16 = 128 B = 8 slots of 16 B; byte addr =
//   row*128 + ((slot ^ (row&7))<<4) + within-slot.
// ---------------------------------------------------------------------------
__global__ __launch_bounds__(256, 3)
void vacf_fused(const float* __restrict__ X, float* __restrict__ partial) {
    const int tid  = threadIdx.x;
    const int lane = tid & 63;
    const int wv   = tid >> 6;
    const int ksix = blockIdx.x % KS;
    const int bb   = blockIdx.x / KS;
    const int i0   = bb * MA;
    const int c0   = ksix * KW;

    __shared__ __align__(16) char lds[SROWS * 128];   // 48 KB
    __shared__ float bins[W];
    if (tid < W) bins[tid] = 0.f;

    // staging map: iter it (0..23): row = it*16 + (tid>>4), cols 4*(tid&15)..+3.
    // Wave-load = 4 rows x 256 B = 4 contiguous segments.
    const int rr = tid >> 4;          // row-in-iter
    const int cl = (tid & 15) * 4;    // col within slice
    // swizzled byte offset within the row: slot = cl>>3, xor row&7 (= rr&7
    // since row = 16*it + rr and 16 == 0 mod 8), plus (cl&7)*2 within slot.
    const int sw = ((((cl >> 3) ^ (rr & 7)) << 4) | ((cl & 7) << 1));

    const bool fast = (i0 + SROWS <= T_DIM) && (c0 + KW <= C_DIM);
    if (fast) {
        #pragma unroll
        for (int b = 0; b < 3; ++b) {
            float4v v[8];
            #pragma unroll
            for (int m = 0; m < 8; ++m) {
                const int row = b * 128 + m * 16 + rr;
                v[m] = *(const float4v*)(X + (size_t)(i0 + row) * C_DIM + c0 + cl);
            }
            #pragma unroll
            for (int m = 0; m < 8; ++m) {
                const int row = b * 128 + m * 16 + rr;
                short4v o;
                o[0] = f2bf(v[m][0]); o[1] = f2bf(v[m][1]);
                o[2] = f2bf(v[m][2]); o[3] = f2bf(v[m][3]);
                *(short4v*)&lds[row * 128 + sw] = o;
            }
        }
    } else {
        #pragma unroll
        for (int b = 0; b < 3; ++b) {
            #pragma unroll
            for (int m = 0; m < 8; ++m) {
                const int row = b * 128 + m * 16 + rr;
                const int gr  = i0 + row;
                float4v v = {0.f, 0.f, 0.f, 0.f};
                if (gr < T_DIM && c0 + cl + 4 <= C_DIM)   // 3000%4==0: no straddle
                    v = *(const float4v*)(X + (size_t)gr * C_DIM + c0 + cl);
                short4v o;
                o[0] = f2bf(v[0]); o[1] = f2bf(v[1]);
                o[2] = f2bf(v[2]); o[3] = f2bf(v[3]);
                *(short4v*)&lds[row * 128 + sw] = o;
            }
        }
    }
    __syncthreads();                          // tile ready (and bins init)

    // compute: subblock rows R = 16s + n; fragment = 8 bf16 at k-chunk kk,
    // k-slot quad. Swizzled addr = R*128 + (((kk*4+quad) ^ (n&7))<<4)
    // (R&7 == n&7). acc0: diagonal d0, acc1: d0+1.
    const int n    = lane & 15;
    const int quad = lane >> 4;
    const int d0   = 2 * wv;

    float4v acc0 = {0.f, 0.f, 0.f, 0.f};
    float4v acc1 = {0.f, 0.f, 0.f, 0.f};

    #pragma unroll
    for (int kk = 0; kk < 2; ++kk) {
        const char* lb = lds + n * 128 + (((((kk << 2) | quad)) ^ (n & 7)) << 4);
        short8 fbp = *(const short8*)(lb + d0 * 2048);       // B subblock d0
        #pragma unroll
        for (int a = 0; a < NA; ++a) {
            const short8 fav = *(const short8*)(lb + a * 2048);
            const short8 fbn = *(const short8*)(lb + (d0 + a + 1) * 2048);
            acc0 = __builtin_amdgcn_mfma_f32_16x16x32_bf16(fav, fbp, acc0, 0, 0, 0);
            acc1 = __builtin_amdgcn_mfma_f32_16x16x32_bf16(fav, fbn, acc1, 0, 0, 0);
            fbp = fbn;
        }
    }

    // epilogue: D[m][n] of diagonal d -> lag t = 16d + n - m  (m = quad*4 + p)
    #pragma unroll
    for (int p = 0; p < 4; ++p) {
        const int m  = quad * 4 + p;
        const int t0 = 16 * d0 + n - m;
        if (t0 >= 0 && t0 < W) atomicAdd(&bins[t0], acc0[p]);
        const int t1 = t0 + 16;
        if (t1 >= 0 && t1 < W) atomicAdd(&bins[t1], acc1[p]);
    }
    __syncthreads();
    if (tid < W) atomicAdd(&partial[(blockIdx.x & 7) * W + tid], bins[tid]);
}

__global__ void vacf_scale(const float* __restrict__ partial, float* __restrict__ out) {
    int t = threadIdx.x;
    if (t < W) {
        float s = 0.f;
        #pragma unroll
        for (int b = 0; b < NPART; ++b) s += partial[b * W + t];
        out[t] = s / ((float)(T_DIM - t) * (float)C_DIM);
    }
}

extern "C" void kernel_launch(void* const* d_in, const int* in_sizes, int n_in,
                              void* d_out, int out_size, void* d_ws, size_t ws_size,
                              hipStream_t stream) {
    const float* X = (const float*)d_in[0];
    float* out = (float*)d_out;
    float* ws  = (float*)d_ws;

    hipMemsetAsync(ws, 0, NPART * W * sizeof(float), stream);
    vacf_fused<<<NBB * KS, 256, 0, stream>>>(X, ws);
    vacf_scale<<<1, 128, 0, stream>>>(ws, out);
}